// Round 2
// baseline (574.839 us; speedup 1.0000x reference)
//
#include <hip/hip_runtime.h>
#include <hip/hip_bf16.h>

using bf16 = __hip_bfloat16;
typedef __attribute__((ext_vector_type(8))) short s16x8;   // 8 bf16 = 4 VGPRs (guide-verified frag type)
typedef __attribute__((ext_vector_type(4))) float f32x4;

// ---- async global->LDS 16B copy (guide m03/m97: wave-uniform LDS base + lane*16) ----
__device__ __forceinline__ void async_cp16(const void* g, void* lds) {
    __builtin_amdgcn_global_load_lds(
        (const __attribute__((address_space(1))) unsigned int*)g,
        (__attribute__((address_space(3))) unsigned int*)lds,
        16, 0, 0);
}

__device__ __forceinline__ void storeC(float* p, float v) { *p = v; }
__device__ __forceinline__ void storeC(bf16* p, float v) { *p = __float2bfloat16(v); }

// ---------------------------------------------------------------------------
// f32 -> bf16 conversion, 4 elements/thread
// ---------------------------------------------------------------------------
__global__ __launch_bounds__(256) void cvt_bf16_kernel(
    const float* __restrict__ src, bf16* __restrict__ dst, int n4)
{
    const int i = blockIdx.x * 256 + threadIdx.x;
    if (i >= n4) return;
    float4 v = ((const float4*)src)[i];
    union { bf16 h[4]; uint2 u; } o;
    o.h[0] = __float2bfloat16(v.x);
    o.h[1] = __float2bfloat16(v.y);
    o.h[2] = __float2bfloat16(v.z);
    o.h[3] = __float2bfloat16(v.w);
    ((uint2*)dst)[i] = o.u;
}

// ---------------------------------------------------------------------------
// NT GEMM: C[M,N] = scale * (A[M,K] @ B[N,K]^T) + bias
//   A, B bf16 row-major; OutT = bf16 or float; bias is f32
//   BIAS: 0 none, 1 bias[col] (n), 2 bias[row] (m)
//   Tile 128x128, BK=64, 256 threads (4 waves, 2x2), 4x4 16x16x32 mfma per wave
// ---------------------------------------------------------------------------
template <typename OutT, int BIAS>
__global__ __launch_bounds__(256) void gemm_nt(
    const bf16* __restrict__ A, const bf16* __restrict__ B,
    OutT* __restrict__ C, const float* __restrict__ bias,
    int M, int N, int K,
    long long sA, long long sB, long long sC,
    float scale)
{
    __shared__ __align__(16) bf16 As[128 * 64];
    __shared__ __align__(16) bf16 Bs[128 * 64];

    const int bz = blockIdx.z;
    A += sA * bz;  B += sB * bz;  C += sC * bz;

    const int m0 = blockIdx.y * 128;
    const int n0 = blockIdx.x * 128;
    const int t = threadIdx.x;
    const int lane = t & 63;
    const int w = t >> 6;              // wave id 0..3
    const int wm = (w >> 1) * 64;      // wave row offset in tile
    const int wn = (w & 1) * 64;       // wave col offset in tile

    f32x4 acc[4][4] = {};

    const bf16* Ag = A + (long long)m0 * K;
    const bf16* Bg = B + (long long)n0 * K;
    // staging: idx = c*256 + t -> row = idx>>3, col8 = idx&7 ; LDS byte off = idx*16
    char* AsB = (char*)As + (size_t)w * 1024;   // + c*4096 per call (wave-uniform)
    char* BsB = (char*)Bs + (size_t)w * 1024;

    for (int k0 = 0; k0 < K; k0 += 64) {
        __syncthreads();   // protect LDS while other waves still compute
        const bf16* a_src = Ag + (long long)(t >> 3) * K + k0 + (t & 7) * 8;
        const bf16* b_src = Bg + (long long)(t >> 3) * K + k0 + (t & 7) * 8;
#pragma unroll
        for (int c = 0; c < 4; ++c) {
            async_cp16(a_src + (long long)(c * 32) * K, AsB + c * 4096);
            async_cp16(b_src + (long long)(c * 32) * K, BsB + c * 4096);
        }
        __syncthreads();   // compiler emits vmcnt(0) drain before s_barrier

#pragma unroll
        for (int kk = 0; kk < 64; kk += 32) {
            const int ko = kk + ((lane >> 4) << 3);   // quad*8
            s16x8 af[4], bfr[4];
#pragma unroll
            for (int i = 0; i < 4; ++i)
                af[i] = *(const s16x8*)(As + (wm + i * 16 + (lane & 15)) * 64 + ko);
#pragma unroll
            for (int j = 0; j < 4; ++j)
                bfr[j] = *(const s16x8*)(Bs + (wn + j * 16 + (lane & 15)) * 64 + ko);
#pragma unroll
            for (int i = 0; i < 4; ++i)
#pragma unroll
                for (int j = 0; j < 4; ++j)
                    acc[i][j] = __builtin_amdgcn_mfma_f32_16x16x32_bf16(
                        af[i], bfr[j], acc[i][j], 0, 0, 0);
        }
    }

    // epilogue: D row = (lane>>4)*4 + r, col = lane&15  (verified m89/m91)
    const int cl = lane & 15;
    const int rquad = (lane >> 4) << 2;
#pragma unroll
    for (int tn = 0; tn < 4; ++tn) {
        const int col = n0 + wn + tn * 16 + cl;
        float bcol = 0.f;
        if constexpr (BIAS == 1) bcol = bias[col];
#pragma unroll
        for (int tm = 0; tm < 4; ++tm) {
#pragma unroll
            for (int r = 0; r < 4; ++r) {
                const int row = m0 + wm + tm * 16 + rquad + r;
                float v = acc[tm][tn][r] * scale;
                if constexpr (BIAS == 1) v += bcol;
                if constexpr (BIAS == 2) v += bias[row];
                storeC(C + (long long)row * N + col, v);
            }
        }
    }
}

// ---------------------------------------------------------------------------
// Per-row softmax stats over 2048 f32 cols: stats[row] = {max, 1/sum(exp(x-max))}
// ---------------------------------------------------------------------------
__global__ __launch_bounds__(256) void row_stats_kernel(
    const float* __restrict__ S, float* __restrict__ stats)
{
    constexpr int NQc = 2048;
    const int row = blockIdx.x, t = threadIdx.x;
    const float* p = S + (long long)row * NQc;
    float v[8];
    float mx = -3.0e38f;
#pragma unroll
    for (int j = 0; j < 8; ++j) { v[j] = p[t + 256 * j]; mx = fmaxf(mx, v[j]); }
#pragma unroll
    for (int off = 32; off > 0; off >>= 1) mx = fmaxf(mx, __shfl_xor(mx, off));
    __shared__ float redm[4];
    __shared__ float reds[4];
    const int lane = t & 63, w = t >> 6;
    if (lane == 0) redm[w] = mx;
    __syncthreads();
    mx = fmaxf(fmaxf(redm[0], redm[1]), fmaxf(redm[2], redm[3]));
    float se = 0.f;
#pragma unroll
    for (int j = 0; j < 8; ++j) se += __expf(v[j] - mx);
#pragma unroll
    for (int off = 32; off > 0; off >>= 1) se += __shfl_xor(se, off);
    if (lane == 0) reds[w] = se;
    __syncthreads();
    se = reds[0] + reds[1] + reds[2] + reds[3];
    if (t == 0) { stats[row * 2] = mx; stats[row * 2 + 1] = 1.0f / se; }
}

// ---------------------------------------------------------------------------
// Normalize + transpose: WT[k,i] = bf16( exp(S[i,k]-m_i) / l_i ), 64x64 tiles
// grid: (NQ/64, NK/64, Z)   S:[Z*NK,NQ] f32, WT:[Z*NQ,NK] bf16
// ---------------------------------------------------------------------------
__global__ __launch_bounds__(256) void softmax_transpose_kernel(
    const float* __restrict__ S, const float* __restrict__ stats, bf16* __restrict__ WT)
{
    constexpr int NQc = 2048, NKc = 2048;
    const int z = blockIdx.z;
    S += (long long)z * NKc * NQc;
    stats += (long long)z * NKc * 2;
    WT += (long long)z * NQc * NKc;

    __shared__ float T[64][65];   // T[k_local][i_local], +1 pad
    const int k0 = blockIdx.x * 64, i0 = blockIdx.y * 64;
    const int t = threadIdx.x;
    const int r = t >> 2;         // local row (i in phase1, k in phase2)
    const int cg = t & 3;         // col group of 16
    const float mi = stats[(i0 + r) * 2];
    const float li = stats[(i0 + r) * 2 + 1];
    const float* src = S + (long long)(i0 + r) * NQc + k0 + cg * 16;
#pragma unroll
    for (int c4 = 0; c4 < 4; ++c4) {
        float4 s4 = *(const float4*)(src + c4 * 4);
        const int cb = cg * 16 + c4 * 4;
        T[cb + 0][r] = __expf(s4.x - mi) * li;
        T[cb + 1][r] = __expf(s4.y - mi) * li;
        T[cb + 2][r] = __expf(s4.z - mi) * li;
        T[cb + 3][r] = __expf(s4.w - mi) * li;
    }
    __syncthreads();
    __align__(16) bf16 tmp[16];
#pragma unroll
    for (int j = 0; j < 16; ++j) tmp[j] = __float2bfloat16(T[r][cg * 16 + j]);
    uint4* dst = (uint4*)(WT + (long long)(k0 + r) * NKc + i0 + cg * 16);
    const uint4* sv = (const uint4*)tmp;
    dst[0] = sv[0];
    dst[1] = sv[1];
}

// ---------------------------------------------------------------------------
extern "C" void kernel_launch(void* const* d_in, const int* in_sizes, int n_in,
                              void* d_out, int out_size, void* d_ws, size_t ws_size,
                              hipStream_t stream)
{
    constexpr int Bb = 8, NK = 2048, NQ = 2048, D = 256, H = 1024;
    const float scale = 0.03125f;   // 1/sqrt(1024)
    constexpr long long NTOK = (long long)Bb * NK;     // 16384
    constexpr long long BIG = NTOK * D;                 // 4,194,304 elements
    constexpr long long WSZ = (long long)H * D;         // 262,144 elements

    const float* KEY   = (const float*)d_in[0];
    const float* VALUE = (const float*)d_in[1];
    const float* QUERY = (const float*)d_in[2];
    const float* Wk_w  = (const float*)d_in[3];
    const float* Wk_b  = (const float*)d_in[4];
    const float* Wq_w  = (const float*)d_in[5];
    const float* Wq_b  = (const float*)d_in[6];
    const float* Wv_w  = (const float*)d_in[7];
    const float* Wv_b  = (const float*)d_in[8];
    const float* lin_w = (const float*)d_in[9];
    const float* lin_b = (const float*)d_in[10];
    float* out = (float*)d_out;

    char* ws = (char*)d_ws;
    bf16* Kp   = (bf16*)ws;  ws += (size_t)Bb * NK * H * 2;        // 33.5 MB
    bf16* Qp   = (bf16*)ws;  ws += (size_t)Bb * NQ * H * 2;        // 33.5 MB
    bf16* VpT  = (bf16*)ws;  ws += (size_t)Bb * H * NK * 2;        // 33.5 MB  [b][h][i]
    bf16* ctx  = (bf16*)ws;  ws += (size_t)Bb * NQ * H * 2;        // 33.5 MB
    float* S2  = (float*)ws; ws += (size_t)2 * NK * NQ * 4;        // 33.5 MB  (batch pair)
    bf16* WT2  = (bf16*)ws;  ws += (size_t)2 * NQ * NK * 2;        // 16.8 MB
    float* st2 = (float*)ws; ws += (size_t)2 * NK * 2 * 4;         // 32 KB
    // bf16 weight copies (kept out of overlap regions; linwb used at the end)
    bf16* Wkb  = (bf16*)ws;  ws += WSZ * 2;                        // 0.5 MB
    bf16* Wqb  = (bf16*)ws;  ws += WSZ * 2;                        // 0.5 MB
    bf16* Wvb  = (bf16*)ws;  ws += WSZ * 2;                        // 0.5 MB
    bf16* linb = (bf16*)ws;  ws += WSZ * 2;                        // 0.5 MB
    // bf16 copies of KEY/VALUE/QUERY live inside the S2 region: they are fully
    // consumed (GEMMs 1-3) before S2 is first written (pair-0 GEMM 4), stream-ordered.
    bf16* KEYb = (bf16*)S2;
    bf16* VALb = KEYb + BIG;
    bf16* QRYb = VALb + BIG;
    // total ws: ~187 MB

    dim3 blk(256);

    // 0: convert f32 -> bf16 (3 big tensors + 4 weight matrices)
    {
        const int n4b = (int)(BIG / 4);            // 1,048,576 threads
        const int n4w = (int)(WSZ / 4);            // 65,536 threads
        cvt_bf16_kernel<<<dim3((n4b + 255) / 256), blk, 0, stream>>>(KEY,   KEYb, n4b);
        cvt_bf16_kernel<<<dim3((n4b + 255) / 256), blk, 0, stream>>>(VALUE, VALb, n4b);
        cvt_bf16_kernel<<<dim3((n4b + 255) / 256), blk, 0, stream>>>(QUERY, QRYb, n4b);
        cvt_bf16_kernel<<<dim3((n4w + 255) / 256), blk, 0, stream>>>(Wk_w,  Wkb,  n4w);
        cvt_bf16_kernel<<<dim3((n4w + 255) / 256), blk, 0, stream>>>(Wq_w,  Wqb,  n4w);
        cvt_bf16_kernel<<<dim3((n4w + 255) / 256), blk, 0, stream>>>(Wv_w,  Wvb,  n4w);
        cvt_bf16_kernel<<<dim3((n4w + 255) / 256), blk, 0, stream>>>(lin_w, linb, n4w);
    }

    // 1,2: projections K,Q  (M=B*NK=16384, N=H, K=D) + col bias
    gemm_nt<bf16, 1><<<dim3(H / 128, Bb * NK / 128, 1), blk, 0, stream>>>(
        KEYb, Wkb, Kp, Wk_b, Bb * NK, H, D, 0, 0, 0, 1.0f);
    gemm_nt<bf16, 1><<<dim3(H / 128, Bb * NQ / 128, 1), blk, 0, stream>>>(
        QRYb, Wqb, Qp, Wq_b, Bb * NQ, H, D, 0, 0, 0, 1.0f);

    // 3: VpT[b,h,i] = Wv_w @ VALUE[b]^T + Wv_b(row)   (M=H, N=NK, K=D, z=batch)
    gemm_nt<bf16, 2><<<dim3(NK / 128, H / 128, Bb), blk, 0, stream>>>(
        Wvb, VALb, VpT, Wv_b, H, NK, D,
        0, (long long)NK * D, (long long)H * NK, 1.0f);

    // 4..7 per batch-pair
    for (int p = 0; p < Bb / 2; ++p) {
        const int b0 = p * 2;
        // 4: S[i,k] = scale * Kp[b] @ Qp[b]^T   (M=NK, N=NQ, K=H, z=2) -> f32
        gemm_nt<float, 0><<<dim3(NQ / 128, NK / 128, 2), blk, 0, stream>>>(
            Kp + (size_t)b0 * NK * H, Qp + (size_t)b0 * NQ * H, S2, nullptr,
            NK, NQ, H,
            (long long)NK * H, (long long)NQ * H, (long long)NK * NQ, scale);
        // 5: per-row stats over k
        row_stats_kernel<<<dim3(2 * NK), blk, 0, stream>>>(S2, st2);
        // 6: normalize + transpose -> WT[k,i] bf16
        softmax_transpose_kernel<<<dim3(NQ / 64, NK / 64, 2), blk, 0, stream>>>(
            S2, st2, WT2);
        // 7: ctx[k,h] = WT @ VpT[b]^T   (M=NQ, N=H, K=NK, z=2)
        gemm_nt<bf16, 0><<<dim3(H / 128, NQ / 128, 2), blk, 0, stream>>>(
            WT2, VpT + (size_t)b0 * H * NK, ctx + (size_t)b0 * NQ * H, nullptr,
            NQ, H, NK,
            (long long)NQ * NK, (long long)H * NK, (long long)NQ * H, 1.0f);
    }

    // 8: out = ctx @ lin_w^T + lin_b   (M=B*NQ, N=D, K=H) -> f32 d_out
    gemm_nt<float, 1><<<dim3(D / 128, Bb * NQ / 128, 1), blk, 0, stream>>>(
        ctx, linb, out, lin_b, Bb * NQ, D, H, 0, 0, 0, 1.0f);
}

// Round 3
// 409.111 us; speedup vs baseline: 1.4051x; 1.4051x over previous
//
#include <hip/hip_runtime.h>
#include <hip/hip_bf16.h>

using bf16 = __hip_bfloat16;
typedef __attribute__((ext_vector_type(8))) short s16x8;   // 8 bf16 = 4 VGPRs
typedef __attribute__((ext_vector_type(4))) float f32x4;

// ---- async global->LDS 16B copy (wave-uniform LDS base + lane*16) ----
__device__ __forceinline__ void async_cp16(const void* g, void* lds) {
    __builtin_amdgcn_global_load_lds(
        (const __attribute__((address_space(1))) unsigned int*)g,
        (__attribute__((address_space(3))) unsigned int*)lds,
        16, 0, 0);
}

__device__ __forceinline__ void storeC(float* p, float v) { *p = v; }
__device__ __forceinline__ void storeC(bf16* p, float v) { *p = __float2bfloat16(v); }

// ---------------------------------------------------------------------------
// f32 -> bf16 conversion, 4 elements/thread
// ---------------------------------------------------------------------------
__global__ __launch_bounds__(256) void cvt_bf16_kernel(
    const float* __restrict__ src, bf16* __restrict__ dst, int n4)
{
    const int i = blockIdx.x * 256 + threadIdx.x;
    if (i >= n4) return;
    float4 v = ((const float4*)src)[i];
    union { bf16 h[4]; uint2 u; } o;
    o.h[0] = __float2bfloat16(v.x);
    o.h[1] = __float2bfloat16(v.y);
    o.h[2] = __float2bfloat16(v.z);
    o.h[3] = __float2bfloat16(v.w);
    ((uint2*)dst)[i] = o.u;
}

// ---------------------------------------------------------------------------
// NT GEMM: C[M,N] = scale * (A[M,K] @ B[N,K]^T) + bias
//   Tile 128xBN, BK=64, 256 threads (4 waves), XOR-swizzled LDS (conflict-free)
//   BIAS: 0 none, 1 bias[col], 2 bias[row]
// ---------------------------------------------------------------------------
template <typename OutT, int BIAS, int BN>
__global__ __launch_bounds__(256) void gemm_nt(
    const bf16* __restrict__ A, const bf16* __restrict__ B,
    OutT* __restrict__ C, const float* __restrict__ bias,
    int M, int N, int K,
    long long sA, long long sB, long long sC,
    float scale)
{
    constexpr int NF = BN / 32;              // B frags per wave (n-dir)
    __shared__ __align__(16) bf16 As[128 * 64];
    __shared__ __align__(16) bf16 Bs[BN * 64];

    const int bz = blockIdx.z;
    A += sA * bz;  B += sB * bz;  C += sC * bz;

    const int m0 = blockIdx.y * 128;
    const int n0 = blockIdx.x * BN;
    const int t = threadIdx.x;
    const int lane = t & 63;
    const int w = t >> 6;                    // wave id 0..3
    const int wm = (w >> 1) * 64;            // wave row offset
    const int wn = (w & 1) * (BN / 2);       // wave col offset

    f32x4 acc[4][NF] = {};

    const bf16* Ag = A + (long long)m0 * K;
    const bf16* Bg = B + (long long)n0 * K;
    // staging: idx = c*256+t -> row = idx>>3 ; SWIZZLED source col8 = (t&7)^(row&7)
    // LDS chunk (row, p) then holds logical col8 = p ^ (row&7)
    const int trow = t >> 3;
    const int tcol = (t & 7) ^ (trow & 7);
    char* AsB = (char*)As + (size_t)w * 1024;    // + c*4096 per call (wave-uniform)
    char* BsB = (char*)Bs + (size_t)w * 1024;

    for (int k0 = 0; k0 < K; k0 += 64) {
        __syncthreads();   // protect LDS while other waves still compute
        const bf16* a_src = Ag + (long long)trow * K + k0 + tcol * 8;
        const bf16* b_src = Bg + (long long)trow * K + k0 + tcol * 8;
#pragma unroll
        for (int c = 0; c < 4; ++c)
            async_cp16(a_src + (long long)(c * 32) * K, AsB + c * 4096);
#pragma unroll
        for (int c = 0; c < NF; ++c)
            async_cp16(b_src + (long long)(c * 32) * K, BsB + c * 4096);
        __syncthreads();   // vmcnt(0) drain before s_barrier

        const int rl = lane & 15;
        const int quad = lane >> 4;
        const int sw = rl & 7;
#pragma unroll
        for (int kk = 0; kk < 64; kk += 32) {
            const int c8 = (kk >> 3) + quad;          // logical col8
            const int ko = ((c8 ^ sw) << 3);          // physical element offset
            s16x8 af[4], bfr[NF];
#pragma unroll
            for (int i = 0; i < 4; ++i)
                af[i] = *(const s16x8*)(As + (wm + i * 16 + rl) * 64 + ko);
#pragma unroll
            for (int j = 0; j < NF; ++j)
                bfr[j] = *(const s16x8*)(Bs + (wn + j * 16 + rl) * 64 + ko);
#pragma unroll
            for (int i = 0; i < 4; ++i)
#pragma unroll
                for (int j = 0; j < NF; ++j)
                    acc[i][j] = __builtin_amdgcn_mfma_f32_16x16x32_bf16(
                        af[i], bfr[j], acc[i][j], 0, 0, 0);
        }
    }

    // epilogue: D row = (lane>>4)*4 + r, col = lane&15  (verified m89/m91)
    const int cl = lane & 15;
    const int rquad = (lane >> 4) << 2;
#pragma unroll
    for (int tn = 0; tn < NF; ++tn) {
        const int col = n0 + wn + tn * 16 + cl;
        float bcol = 0.f;
        if constexpr (BIAS == 1) bcol = bias[col];
#pragma unroll
        for (int tm = 0; tm < 4; ++tm) {
#pragma unroll
            for (int r = 0; r < 4; ++r) {
                const int row = m0 + wm + tm * 16 + rquad + r;
                float v = acc[tm][tn][r] * scale;
                if constexpr (BIAS == 1) v += bcol;
                if constexpr (BIAS == 2) v += bias[row];
                storeC(C + (long long)row * N + col, v);
            }
        }
    }
}

// ---------------------------------------------------------------------------
// Per-row softmax stats over 2048 bf16 cols: stats[row] = {max, 1/sum(exp)}
// ---------------------------------------------------------------------------
__global__ __launch_bounds__(256) void row_stats_kernel(
    const bf16* __restrict__ S, float* __restrict__ stats)
{
    constexpr int NQc = 2048;
    const int row = blockIdx.x, t = threadIdx.x;
    const bf16* p = S + (long long)row * NQc + t * 8;
    union { uint4 u; bf16 h[8]; } in;
    in.u = *(const uint4*)p;
    float v[8];
    float mx = -3.0e38f;
#pragma unroll
    for (int j = 0; j < 8; ++j) { v[j] = __bfloat162float(in.h[j]); mx = fmaxf(mx, v[j]); }
#pragma unroll
    for (int off = 32; off > 0; off >>= 1) mx = fmaxf(mx, __shfl_xor(mx, off));
    __shared__ float redm[4];
    __shared__ float reds[4];
    const int lane = t & 63, w = t >> 6;
    if (lane == 0) redm[w] = mx;
    __syncthreads();
    mx = fmaxf(fmaxf(redm[0], redm[1]), fmaxf(redm[2], redm[3]));
    float se = 0.f;
#pragma unroll
    for (int j = 0; j < 8; ++j) se += __expf(v[j] - mx);
#pragma unroll
    for (int off = 32; off > 0; off >>= 1) se += __shfl_xor(se, off);
    if (lane == 0) reds[w] = se;
    __syncthreads();
    se = reds[0] + reds[1] + reds[2] + reds[3];
    if (t == 0) { stats[row * 2] = mx; stats[row * 2 + 1] = 1.0f / se; }
}

// ---------------------------------------------------------------------------
// Normalize + transpose: WT[k,i] = bf16( exp(S[i,k]-m_i) / l_i ), 64x64 tiles
// grid: (NQ/64, NK/64, Z)   S:[Z,NK,NQ] bf16, WT:[Z,NQ,NK] bf16
// ---------------------------------------------------------------------------
__global__ __launch_bounds__(256) void softmax_transpose_kernel(
    const bf16* __restrict__ S, const float* __restrict__ stats, bf16* __restrict__ WT)
{
    constexpr int NQc = 2048, NKc = 2048;
    const int z = blockIdx.z;
    S += (long long)z * NKc * NQc;
    stats += (long long)z * NKc * 2;
    WT += (long long)z * NQc * NKc;

    __shared__ float T[64][65];   // T[k_local][i_local], +1 pad
    const int k0 = blockIdx.x * 64, i0 = blockIdx.y * 64;
    const int t = threadIdx.x;
    const int r = t >> 2;         // local row (i in phase1, k in phase2)
    const int cg = t & 3;         // col group of 16
    const float mi = stats[(i0 + r) * 2];
    const float li = stats[(i0 + r) * 2 + 1];
    const bf16* src = S + (long long)(i0 + r) * NQc + k0 + cg * 16;
    union { uint4 u; bf16 h[8]; } in;
#pragma unroll
    for (int c8 = 0; c8 < 2; ++c8) {
        in.u = *(const uint4*)(src + c8 * 8);
        const int cb = cg * 16 + c8 * 8;
#pragma unroll
        for (int j = 0; j < 8; ++j)
            T[cb + j][r] = __expf(__bfloat162float(in.h[j]) - mi) * li;
    }
    __syncthreads();
    __align__(16) bf16 tmp[16];
#pragma unroll
    for (int j = 0; j < 16; ++j) tmp[j] = __float2bfloat16(T[r][cg * 16 + j]);
    uint4* dst = (uint4*)(WT + (long long)(k0 + r) * NKc + i0 + cg * 16);
    const uint4* sv = (const uint4*)tmp;
    dst[0] = sv[0];
    dst[1] = sv[1];
}

// ---------------------------------------------------------------------------
extern "C" void kernel_launch(void* const* d_in, const int* in_sizes, int n_in,
                              void* d_out, int out_size, void* d_ws, size_t ws_size,
                              hipStream_t stream)
{
    constexpr int Bb = 8, NK = 2048, NQ = 2048, D = 256, H = 1024;
    const float scale = 0.03125f;   // 1/sqrt(1024)
    constexpr size_t E1  = (size_t)Bb * NK * H;   // 16,777,216 elems (33.55 MB bf16)
    constexpr size_t ES  = (size_t)NK * NQ;       // 4,194,304 elems per batch
    constexpr size_t BIG = (size_t)Bb * NK * D;   // 4,194,304 elems
    constexpr size_t WSZ = (size_t)H * D;         // 262,144 elems
    constexpr size_t MISC = 8 * 2048 * 2 * 4 + 4 * WSZ * 2;   // stats + bf16 weights

    const float* KEY   = (const float*)d_in[0];
    const float* VALUE = (const float*)d_in[1];
    const float* QUERY = (const float*)d_in[2];
    const float* Wk_w  = (const float*)d_in[3];
    const float* Wk_b  = (const float*)d_in[4];
    const float* Wq_w  = (const float*)d_in[5];
    const float* Wq_b  = (const float*)d_in[6];
    const float* Wv_w  = (const float*)d_in[7];
    const float* Wv_b  = (const float*)d_in[8];
    const float* lin_w = (const float*)d_in[9];
    const float* lin_b = (const float*)d_in[10];
    float* out = (float*)d_out;

    // group size: largest g whose workspace fits (deterministic across calls)
    auto need = [&](int g) -> size_t {
        return 3 * E1 * 2 + (g < 8 ? E1 * 2 : 0) + 2 * (size_t)g * ES * 2 + MISC;
    };
    const int g = (ws_size >= need(8)) ? 8 : (ws_size >= need(4)) ? 4 : 2;

    char* ws = (char*)d_ws;
    bf16* Kp   = (bf16*)ws;  ws += E1 * 2;
    bf16* Qp   = (bf16*)ws;  ws += E1 * 2;
    bf16* VpT  = (bf16*)ws;  ws += E1 * 2;                 // [b][h][i]
    bf16* ctx  = Kp;                                       // g==8: alias dead Kp
    if (g < 8) { ctx = (bf16*)ws; ws += E1 * 2; }
    bf16* Sg   = (bf16*)ws;  ws += (size_t)g * ES * 2;     // scores, bf16
    bf16* WTg  = (bf16*)ws;  ws += (size_t)g * ES * 2;     // transposed weights
    float* st  = (float*)ws; ws += 8 * 2048 * 2 * 4;
    bf16* Wkb  = (bf16*)ws;  ws += WSZ * 2;
    bf16* Wqb  = (bf16*)ws;  ws += WSZ * 2;
    bf16* Wvb  = (bf16*)ws;  ws += WSZ * 2;
    bf16* linb = (bf16*)ws;  ws += WSZ * 2;
    // bf16 input copies overlay Sg(+WTg): fully consumed by GEMMs 1-3 before
    // Sg/WTg are first written (stream-ordered). Sg+WTg >= 33.5 MB >= 25.2 MB.
    bf16* KEYb = Sg;
    bf16* VALb = KEYb + BIG;
    bf16* QRYb = VALb + BIG;

    dim3 blk(256);

    // 0: convert f32 -> bf16
    {
        const int n4b = (int)(BIG / 4), n4w = (int)(WSZ / 4);
        cvt_bf16_kernel<<<dim3(n4b / 256), blk, 0, stream>>>(KEY,   KEYb, n4b);
        cvt_bf16_kernel<<<dim3(n4b / 256), blk, 0, stream>>>(VALUE, VALb, n4b);
        cvt_bf16_kernel<<<dim3(n4b / 256), blk, 0, stream>>>(QUERY, QRYb, n4b);
        cvt_bf16_kernel<<<dim3(n4w / 256), blk, 0, stream>>>(Wk_w,  Wkb,  n4w);
        cvt_bf16_kernel<<<dim3(n4w / 256), blk, 0, stream>>>(Wq_w,  Wqb,  n4w);
        cvt_bf16_kernel<<<dim3(n4w / 256), blk, 0, stream>>>(Wv_w,  Wvb,  n4w);
        cvt_bf16_kernel<<<dim3(n4w / 256), blk, 0, stream>>>(lin_w, linb, n4w);
    }

    // 1,2: projections K,Q  (M=16384, N=H, K=D) + col bias
    gemm_nt<bf16, 1, 128><<<dim3(H / 128, Bb * NK / 128, 1), blk, 0, stream>>>(
        KEYb, Wkb, Kp, Wk_b, Bb * NK, H, D, 0, 0, 0, 1.0f);
    gemm_nt<bf16, 1, 128><<<dim3(H / 128, Bb * NQ / 128, 1), blk, 0, stream>>>(
        QRYb, Wqb, Qp, Wq_b, Bb * NQ, H, D, 0, 0, 0, 1.0f);

    // 3: VpT[b,h,i] = Wv_w @ VALUE[b]^T + Wv_b(row)   (M=H, N=NK, K=D, z=batch)
    gemm_nt<bf16, 2, 128><<<dim3(NK / 128, H / 128, Bb), blk, 0, stream>>>(
        Wvb, VALb, VpT, Wv_b, H, NK, D,
        0, (long long)NK * D, (long long)H * NK, 1.0f);

    // 4..7 per group of g batches
    for (int b0 = 0; b0 < Bb; b0 += g) {
        // 4: S[i,k] = scale * Kp[b] @ Qp[b]^T  -> bf16   (z=g)
        gemm_nt<bf16, 0, 128><<<dim3(NQ / 128, NK / 128, g), blk, 0, stream>>>(
            Kp + (size_t)b0 * NK * H, Qp + (size_t)b0 * NQ * H, Sg, nullptr,
            NK, NQ, H,
            (long long)NK * H, (long long)NQ * H, (long long)NK * NQ, scale);
        // 5: per-row stats over k
        row_stats_kernel<<<dim3(g * NK), blk, 0, stream>>>(Sg, st);
        // 6: normalize + transpose -> WT[k,i] bf16
        softmax_transpose_kernel<<<dim3(NQ / 64, NK / 64, g), blk, 0, stream>>>(
            Sg, st, WTg);
        // 7: ctx[k,h] = WT @ VpT[b]^T   (M=NQ, N=H, K=NK, z=g)
        gemm_nt<bf16, 0, 128><<<dim3(H / 128, NQ / 128, g), blk, 0, stream>>>(
            WTg, VpT + (size_t)b0 * H * NK, ctx + (size_t)b0 * NQ * H, nullptr,
            NQ, H, NK,
            (long long)NQ * NK, (long long)H * NK, (long long)NQ * H, 1.0f);
    }

    // 8: out = ctx @ lin_w^T + lin_b   (M=16384, N=D, K=H) -> f32 d_out, BN=64
    gemm_nt<float, 1, 64><<<dim3(D / 64, Bb * NQ / 128, 1), blk, 0, stream>>>(
        ctx, linb, out, lin_b, Bb * NQ, D, H, 0, 0, 0, 1.0f);
}

// Round 4
// 405.158 us; speedup vs baseline: 1.4188x; 1.0098x over previous
//
#include <hip/hip_runtime.h>
#include <hip/hip_bf16.h>

using bf16 = __hip_bfloat16;
typedef __attribute__((ext_vector_type(8))) short s16x8;   // 8 bf16 = 4 VGPRs
typedef __attribute__((ext_vector_type(4))) float f32x4;

// ---- async global->LDS 16B copy (wave-uniform LDS base + lane*16) ----
__device__ __forceinline__ void async_cp16(const void* g, void* lds) {
    __builtin_amdgcn_global_load_lds(
        (const __attribute__((address_space(1))) unsigned int*)g,
        (__attribute__((address_space(3))) unsigned int*)lds,
        16, 0, 0);
}

__device__ __forceinline__ void storeC(float* p, float v) { *p = v; }
__device__ __forceinline__ void storeC(bf16* p, float v) { *p = __float2bfloat16(v); }

// ---------------------------------------------------------------------------
// f32 -> bf16 conversion, 4 elements/thread
// ---------------------------------------------------------------------------
__global__ __launch_bounds__(256) void cvt_bf16_kernel(
    const float* __restrict__ src, bf16* __restrict__ dst, int n4)
{
    const int i = blockIdx.x * 256 + threadIdx.x;
    if (i >= n4) return;
    float4 v = ((const float4*)src)[i];
    union { bf16 h[4]; uint2 u; } o;
    o.h[0] = __float2bfloat16(v.x);
    o.h[1] = __float2bfloat16(v.y);
    o.h[2] = __float2bfloat16(v.z);
    o.h[3] = __float2bfloat16(v.w);
    ((uint2*)dst)[i] = o.u;
}

// ---------------------------------------------------------------------------
// NT GEMM: C[M,N] = scale * (A[M,K] @ B[N,K]^T) + bias
//   Tile 128xBN, BK=64, 256 threads (4 waves), XOR-swizzled LDS (conflict-free)
//   BIAS: 0 none, 1 bias[col], 2 bias[row]
//   SWZ: 1 = 1-D grid, z = bid % nz (XCD binding), GROUP_M=4 tile order
// ---------------------------------------------------------------------------
template <typename OutT, int BIAS, int BN, int SWZ = 0>
__global__ __launch_bounds__(256) void gemm_nt(
    const bf16* __restrict__ A, const bf16* __restrict__ B,
    OutT* __restrict__ C, const float* __restrict__ bias,
    int M, int N, int K,
    long long sA, long long sB, long long sC,
    float scale, int nz, int npn)
{
    constexpr int NF = BN / 32;              // B frags per wave (n-dir)
    __shared__ __align__(16) bf16 As[128 * 64];
    __shared__ __align__(16) bf16 Bs[BN * 64];

    int bz, m0, n0;
    if constexpr (SWZ) {
        const int bid = blockIdx.x;
        bz = bid % nz;                        // bind batch -> XCD (round-robin)
        const int t0 = bid / nz;
        const int grp = t0 / (4 * npn);       // GROUP_M = 4
        m0 = (grp * 4 + (t0 % 4)) * 128;
        n0 = ((t0 / 4) % npn) * BN;
    } else {
        bz = blockIdx.z;
        m0 = blockIdx.y * 128;
        n0 = blockIdx.x * BN;
    }
    A += sA * bz;  B += sB * bz;  C += sC * bz;

    const int t = threadIdx.x;
    const int lane = t & 63;
    const int w = t >> 6;                    // wave id 0..3
    const int wm = (w >> 1) * 64;            // wave row offset
    const int wn = (w & 1) * (BN / 2);       // wave col offset

    f32x4 acc[4][NF] = {};

    const bf16* Ag = A + (long long)m0 * K;
    const bf16* Bg = B + (long long)n0 * K;
    // staging: idx = c*256+t -> row = idx>>3 ; SWIZZLED source col8 = (t&7)^(row&7)
    // LDS chunk (row, p) then holds logical col8 = p ^ (row&7)
    const int trow = t >> 3;
    const int tcol = (t & 7) ^ (trow & 7);
    char* AsB = (char*)As + (size_t)w * 1024;    // + c*4096 per call (wave-uniform)
    char* BsB = (char*)Bs + (size_t)w * 1024;

    for (int k0 = 0; k0 < K; k0 += 64) {
        __syncthreads();   // protect LDS while other waves still compute
        const bf16* a_src = Ag + (long long)trow * K + k0 + tcol * 8;
        const bf16* b_src = Bg + (long long)trow * K + k0 + tcol * 8;
#pragma unroll
        for (int c = 0; c < 4; ++c)
            async_cp16(a_src + (long long)(c * 32) * K, AsB + c * 4096);
#pragma unroll
        for (int c = 0; c < NF; ++c)
            async_cp16(b_src + (long long)(c * 32) * K, BsB + c * 4096);
        __syncthreads();   // vmcnt(0) drain before s_barrier

        const int rl = lane & 15;
        const int quad = lane >> 4;
        const int sw = rl & 7;
#pragma unroll
        for (int kk = 0; kk < 64; kk += 32) {
            const int c8 = (kk >> 3) + quad;          // logical col8
            const int ko = ((c8 ^ sw) << 3);          // physical element offset
            s16x8 af[4], bfr[NF];
#pragma unroll
            for (int i = 0; i < 4; ++i)
                af[i] = *(const s16x8*)(As + (wm + i * 16 + rl) * 64 + ko);
#pragma unroll
            for (int j = 0; j < NF; ++j)
                bfr[j] = *(const s16x8*)(Bs + (wn + j * 16 + rl) * 64 + ko);
#pragma unroll
            for (int i = 0; i < 4; ++i)
#pragma unroll
                for (int j = 0; j < NF; ++j)
                    acc[i][j] = __builtin_amdgcn_mfma_f32_16x16x32_bf16(
                        af[i], bfr[j], acc[i][j], 0, 0, 0);
        }
    }

    // epilogue: D row = (lane>>4)*4 + r, col = lane&15  (verified m89/m91)
    const int cl = lane & 15;
    const int rquad = (lane >> 4) << 2;
#pragma unroll
    for (int tn = 0; tn < NF; ++tn) {
        const int col = n0 + wn + tn * 16 + cl;
        float bcol = 0.f;
        if constexpr (BIAS == 1) bcol = bias[col];
#pragma unroll
        for (int tm = 0; tm < 4; ++tm) {
#pragma unroll
            for (int r = 0; r < 4; ++r) {
                const int row = m0 + wm + tm * 16 + rquad + r;
                float v = acc[tm][tn][r] * scale;
                if constexpr (BIAS == 1) v += bcol;
                if constexpr (BIAS == 2) v += bias[row];
                storeC(C + (long long)row * N + col, v);
            }
        }
    }
}

// ---------------------------------------------------------------------------
// Per-row softmax stats over 2048 bf16 cols: stats[row] = {max, 1/sum(exp)}
// ---------------------------------------------------------------------------
__global__ __launch_bounds__(256) void row_stats_kernel(
    const bf16* __restrict__ S, float* __restrict__ stats)
{
    constexpr int NQc = 2048;
    const int row = blockIdx.x, t = threadIdx.x;
    const bf16* p = S + (long long)row * NQc + t * 8;
    union { uint4 u; bf16 h[8]; } in;
    in.u = *(const uint4*)p;
    float v[8];
    float mx = -3.0e38f;
#pragma unroll
    for (int j = 0; j < 8; ++j) { v[j] = __bfloat162float(in.h[j]); mx = fmaxf(mx, v[j]); }
#pragma unroll
    for (int off = 32; off > 0; off >>= 1) mx = fmaxf(mx, __shfl_xor(mx, off));
    __shared__ float redm[4];
    __shared__ float reds[4];
    const int lane = t & 63, w = t >> 6;
    if (lane == 0) redm[w] = mx;
    __syncthreads();
    mx = fmaxf(fmaxf(redm[0], redm[1]), fmaxf(redm[2], redm[3]));
    float se = 0.f;
#pragma unroll
    for (int j = 0; j < 8; ++j) se += __expf(v[j] - mx);
#pragma unroll
    for (int off = 32; off > 0; off >>= 1) se += __shfl_xor(se, off);
    if (lane == 0) reds[w] = se;
    __syncthreads();
    se = reds[0] + reds[1] + reds[2] + reds[3];
    if (t == 0) { stats[row * 2] = mx; stats[row * 2 + 1] = 1.0f / se; }
}

// ---------------------------------------------------------------------------
// Normalize + transpose: WT[k,i] = bf16( exp(S[i,k]-m_i) / l_i ), 64x64 tiles
// grid: (NQ/64, NK/64, Z)   S:[Z,NK,NQ] bf16, WT:[Z,NQ,NK] bf16
// ---------------------------------------------------------------------------
__global__ __launch_bounds__(256) void softmax_transpose_kernel(
    const bf16* __restrict__ S, const float* __restrict__ stats, bf16* __restrict__ WT)
{
    constexpr int NQc = 2048, NKc = 2048;
    const int z = blockIdx.z;
    S += (long long)z * NKc * NQc;
    stats += (long long)z * NKc * 2;
    WT += (long long)z * NQc * NKc;

    __shared__ float T[64][65];   // T[k_local][i_local], +1 pad
    const int k0 = blockIdx.x * 64, i0 = blockIdx.y * 64;
    const int t = threadIdx.x;
    const int r = t >> 2;         // local row (i in phase1, k in phase2)
    const int cg = t & 3;         // col group of 16
    const float mi = stats[(i0 + r) * 2];
    const float li = stats[(i0 + r) * 2 + 1];
    const bf16* src = S + (long long)(i0 + r) * NQc + k0 + cg * 16;
    union { uint4 u; bf16 h[8]; } in;
#pragma unroll
    for (int c8 = 0; c8 < 2; ++c8) {
        in.u = *(const uint4*)(src + c8 * 8);
        const int cb = cg * 16 + c8 * 8;
#pragma unroll
        for (int j = 0; j < 8; ++j)
            T[cb + j][r] = __expf(__bfloat162float(in.h[j]) - mi) * li;
    }
    __syncthreads();
    __align__(16) bf16 tmp[16];
#pragma unroll
    for (int j = 0; j < 16; ++j) tmp[j] = __float2bfloat16(T[r][cg * 16 + j]);
    uint4* dst = (uint4*)(WT + (long long)(k0 + r) * NKc + i0 + cg * 16);
    const uint4* sv = (const uint4*)tmp;
    dst[0] = sv[0];
    dst[1] = sv[1];
}

// ---------------------------------------------------------------------------
extern "C" void kernel_launch(void* const* d_in, const int* in_sizes, int n_in,
                              void* d_out, int out_size, void* d_ws, size_t ws_size,
                              hipStream_t stream)
{
    constexpr int Bb = 8, NK = 2048, NQ = 2048, D = 256, H = 1024;
    const float scale = 0.03125f;   // 1/sqrt(1024)
    constexpr size_t E1  = (size_t)Bb * NK * H;   // 16,777,216 elems (33.55 MB bf16)
    constexpr size_t ES  = (size_t)NK * NQ;       // 4,194,304 elems per batch
    constexpr size_t BIG = (size_t)Bb * NK * D;   // 4,194,304 elems
    constexpr size_t WSZ = (size_t)H * D;         // 262,144 elems
    constexpr size_t MISC = 8 * 2048 * 2 * 4 + 4 * WSZ * 2;   // stats + bf16 weights

    const float* KEY   = (const float*)d_in[0];
    const float* VALUE = (const float*)d_in[1];
    const float* QUERY = (const float*)d_in[2];
    const float* Wk_w  = (const float*)d_in[3];
    const float* Wk_b  = (const float*)d_in[4];
    const float* Wq_w  = (const float*)d_in[5];
    const float* Wq_b  = (const float*)d_in[6];
    const float* Wv_w  = (const float*)d_in[7];
    const float* Wv_b  = (const float*)d_in[8];
    const float* lin_w = (const float*)d_in[9];
    const float* lin_b = (const float*)d_in[10];
    float* out = (float*)d_out;

    // group size: largest g whose workspace fits (deterministic across calls)
    auto need = [&](int g) -> size_t {
        return 3 * E1 * 2 + (g < 8 ? E1 * 2 : 0) + 2 * (size_t)g * ES * 2 + MISC;
    };
    const int g = (ws_size >= need(8)) ? 8 : (ws_size >= need(4)) ? 4 : 2;

    char* ws = (char*)d_ws;
    bf16* Kp   = (bf16*)ws;  ws += E1 * 2;
    bf16* Qp   = (bf16*)ws;  ws += E1 * 2;
    bf16* VpT  = (bf16*)ws;  ws += E1 * 2;                 // [b][h][i]
    bf16* ctx  = Kp;                                       // g==8: alias dead Kp
    if (g < 8) { ctx = (bf16*)ws; ws += E1 * 2; }
    bf16* Sg   = (bf16*)ws;  ws += (size_t)g * ES * 2;     // scores, bf16
    bf16* WTg  = (bf16*)ws;  ws += (size_t)g * ES * 2;     // transposed weights
    float* st  = (float*)ws; ws += 8 * 2048 * 2 * 4;
    bf16* Wkb  = (bf16*)ws;  ws += WSZ * 2;
    bf16* Wqb  = (bf16*)ws;  ws += WSZ * 2;
    bf16* Wvb  = (bf16*)ws;  ws += WSZ * 2;
    bf16* linb = (bf16*)ws;  ws += WSZ * 2;
    // bf16 input copies overlay Sg(+WTg): fully consumed by GEMMs 1-3 before
    // Sg/WTg are first written (stream-ordered).
    bf16* KEYb = Sg;
    bf16* VALb = KEYb + BIG;
    bf16* QRYb = VALb + BIG;

    dim3 blk(256);

    // 0: convert f32 -> bf16
    {
        const int n4b = (int)(BIG / 4), n4w = (int)(WSZ / 4);
        cvt_bf16_kernel<<<dim3(n4b / 256), blk, 0, stream>>>(KEY,   KEYb, n4b);
        cvt_bf16_kernel<<<dim3(n4b / 256), blk, 0, stream>>>(VALUE, VALb, n4b);
        cvt_bf16_kernel<<<dim3(n4b / 256), blk, 0, stream>>>(QUERY, QRYb, n4b);
        cvt_bf16_kernel<<<dim3(n4w / 256), blk, 0, stream>>>(Wk_w,  Wkb,  n4w);
        cvt_bf16_kernel<<<dim3(n4w / 256), blk, 0, stream>>>(Wq_w,  Wqb,  n4w);
        cvt_bf16_kernel<<<dim3(n4w / 256), blk, 0, stream>>>(Wv_w,  Wvb,  n4w);
        cvt_bf16_kernel<<<dim3(n4w / 256), blk, 0, stream>>>(lin_w, linb, n4w);
    }

    // 1,2: projections K,Q  (M=16384, N=H, K=D) + col bias
    gemm_nt<bf16, 1, 128><<<dim3(H / 128, Bb * NK / 128, 1), blk, 0, stream>>>(
        KEYb, Wkb, Kp, Wk_b, Bb * NK, H, D, 0, 0, 0, 1.0f, 1, 1);
    gemm_nt<bf16, 1, 128><<<dim3(H / 128, Bb * NQ / 128, 1), blk, 0, stream>>>(
        QRYb, Wqb, Qp, Wq_b, Bb * NQ, H, D, 0, 0, 0, 1.0f, 1, 1);

    // 3: VpT[b,h,i] = Wv_w @ VALUE[b]^T + Wv_b(row)   (M=H, N=NK, K=D, z=batch)
    gemm_nt<bf16, 2, 128><<<dim3(NK / 128, H / 128, Bb), blk, 0, stream>>>(
        Wvb, VALb, VpT, Wv_b, H, NK, D,
        0, (long long)NK * D, (long long)H * NK, 1.0f, 1, 1);

    // 4..7 per group of g batches
    for (int b0 = 0; b0 < Bb; b0 += g) {
        // 4: S[i,k] = scale * Kp[b] @ Qp[b]^T  -> bf16  (1-D swizzled grid, z=bid%g)
        gemm_nt<bf16, 0, 128, 1><<<dim3(g * (NK / 128) * (NQ / 128)), blk, 0, stream>>>(
            Kp + (size_t)b0 * NK * H, Qp + (size_t)b0 * NQ * H, Sg, nullptr,
            NK, NQ, H,
            (long long)NK * H, (long long)NQ * H, (long long)NK * NQ, scale,
            g, NQ / 128);
        // 5: per-row stats over k
        row_stats_kernel<<<dim3(g * NK), blk, 0, stream>>>(Sg, st);
        // 6: normalize + transpose -> WT[k,i] bf16
        softmax_transpose_kernel<<<dim3(NQ / 64, NK / 64, g), blk, 0, stream>>>(
            Sg, st, WTg);
        // 7: ctx[k,h] = WT @ VpT[b]^T   (M=NQ, N=H, K=NK, swizzled, z=bid%g)
        gemm_nt<bf16, 0, 128, 1><<<dim3(g * (NQ / 128) * (H / 128)), blk, 0, stream>>>(
            WTg, VpT + (size_t)b0 * H * NK, ctx + (size_t)b0 * NQ * H, nullptr,
            NQ, H, NK,
            (long long)NQ * NK, (long long)H * NK, (long long)NQ * H, 1.0f,
            g, H / 128);
    }

    // 8: out = ctx @ lin_w^T + lin_b   (M=16384, N=D, K=H) -> f32 d_out, BN=64
    gemm_nt<float, 1, 64><<<dim3(D / 64, Bb * NQ / 128, 1), blk, 0, stream>>>(
        ctx, linb, out, lin_b, Bb * NQ, D, H, 0, 0, 0, 1.0f, 1, 1);
}

// Round 5
// 373.499 us; speedup vs baseline: 1.5391x; 1.0848x over previous
//
#include <hip/hip_runtime.h>
#include <hip/hip_bf16.h>

using bf16 = __hip_bfloat16;
typedef __attribute__((ext_vector_type(8))) short s16x8;   // 8 bf16 = 4 VGPRs
typedef __attribute__((ext_vector_type(4))) float f32x4;

// ---- async global->LDS 16B copy (wave-uniform LDS base + lane*16) ----
__device__ __forceinline__ void async_cp16(const void* g, void* lds) {
    __builtin_amdgcn_global_load_lds(
        (const __attribute__((address_space(1))) unsigned int*)g,
        (__attribute__((address_space(3))) unsigned int*)lds,
        16, 0, 0);
}

__device__ __forceinline__ void storeC(float* p, float v) { *p = v; }
__device__ __forceinline__ void storeC(bf16* p, float v) { *p = __float2bfloat16(v); }

// ---------------------------------------------------------------------------
// f32 -> bf16 conversion, 4 elements/thread; blockIdx.y selects src tensor
// ---------------------------------------------------------------------------
__global__ __launch_bounds__(256) void cvt3_kernel(
    const float* __restrict__ s0, const float* __restrict__ s1,
    const float* __restrict__ s2, bf16* __restrict__ dst, int n4)
{
    const int i = blockIdx.x * 256 + threadIdx.x;
    if (i >= n4) return;
    const float* src = (blockIdx.y == 0) ? s0 : (blockIdx.y == 1) ? s1 : s2;
    float4 v = ((const float4*)src)[i];
    union { bf16 h[4]; uint2 u; } o;
    o.h[0] = __float2bfloat16(v.x);
    o.h[1] = __float2bfloat16(v.y);
    o.h[2] = __float2bfloat16(v.z);
    o.h[3] = __float2bfloat16(v.w);
    ((uint2*)(dst + (size_t)blockIdx.y * (size_t)n4 * 4))[i] = o.u;
}

__global__ __launch_bounds__(256) void cvt4_kernel(
    const float* __restrict__ s0, const float* __restrict__ s1,
    const float* __restrict__ s2, const float* __restrict__ s3,
    bf16* __restrict__ dst, int n4)
{
    const int i = blockIdx.x * 256 + threadIdx.x;
    if (i >= n4) return;
    const float* src = (blockIdx.y == 0) ? s0 : (blockIdx.y == 1) ? s1
                     : (blockIdx.y == 2) ? s2 : s3;
    float4 v = ((const float4*)src)[i];
    union { bf16 h[4]; uint2 u; } o;
    o.h[0] = __float2bfloat16(v.x);
    o.h[1] = __float2bfloat16(v.y);
    o.h[2] = __float2bfloat16(v.z);
    o.h[3] = __float2bfloat16(v.w);
    ((uint2*)(dst + (size_t)blockIdx.y * (size_t)n4 * 4))[i] = o.u;
}

__global__ __launch_bounds__(256) void zero_kernel(float* __restrict__ p, int n4)
{
    const int i = blockIdx.x * 256 + threadIdx.x;
    if (i < n4) ((float4*)p)[i] = float4{0.f, 0.f, 0.f, 0.f};
}

// ---------------------------------------------------------------------------
// VpS[h,i] = VpT[h,i] / colsum[z*NK + i]   (8 elems/thread along i)
// ---------------------------------------------------------------------------
__global__ __launch_bounds__(256) void scale_cols_kernel(
    const bf16* __restrict__ VpT, const float* __restrict__ colsum,
    bf16* __restrict__ VpS, int HN, int NKc)
{
    const long long idx = ((long long)blockIdx.x * 256 + threadIdx.x) * 8;
    const int z = (int)(idx / HN);
    const int i = (int)(idx % NKc);
    union { uint4 u; bf16 h[8]; } in, o;
    in.u = *(const uint4*)(VpT + idx);
    const float4 c0 = *(const float4*)(colsum + (long long)z * NKc + i);
    const float4 c1 = *(const float4*)(colsum + (long long)z * NKc + i + 4);
    o.h[0] = __float2bfloat16(__bfloat162float(in.h[0]) / c0.x);
    o.h[1] = __float2bfloat16(__bfloat162float(in.h[1]) / c0.y);
    o.h[2] = __float2bfloat16(__bfloat162float(in.h[2]) / c0.z);
    o.h[3] = __float2bfloat16(__bfloat162float(in.h[3]) / c0.w);
    o.h[4] = __float2bfloat16(__bfloat162float(in.h[4]) / c1.x);
    o.h[5] = __float2bfloat16(__bfloat162float(in.h[5]) / c1.y);
    o.h[6] = __float2bfloat16(__bfloat162float(in.h[6]) / c1.z);
    o.h[7] = __float2bfloat16(__bfloat162float(in.h[7]) / c1.w);
    *(uint4*)(VpS + idx) = o.u;
}

// ---------------------------------------------------------------------------
// NT GEMM: C[M,N] = scale * (A[M,K] @ B[N,K]^T) + bias
//   Tile 128xBN, BK=64, 256 threads (4 waves), XOR-swizzled LDS (conflict-free)
//   BIAS: 0 none, 1 bias[col], 2 bias[row]
//   SWZ: 1 = 1-D grid, z = bid % nz (XCD binding), GROUP_M=4 tile order
//   EXP: 1 = write exp(acc*scale), atomic per-column sums into colsum[bz*N+col]
// ---------------------------------------------------------------------------
template <typename OutT, int BIAS, int BN, int SWZ = 0, int EXP = 0>
__global__ __launch_bounds__(256) void gemm_nt(
    const bf16* __restrict__ A, const bf16* __restrict__ B,
    OutT* __restrict__ C, const float* __restrict__ bias,
    float* __restrict__ colsum,
    int M, int N, int K,
    long long sA, long long sB, long long sC,
    float scale, int nz, int npn)
{
    constexpr int NF = BN / 32;              // B frags per wave (n-dir)
    __shared__ __align__(16) bf16 As[128 * 64];
    __shared__ __align__(16) bf16 Bs[BN * 64];

    int bz, m0, n0;
    if constexpr (SWZ) {
        const int bid = blockIdx.x;
        bz = bid % nz;                        // bind batch -> XCD (round-robin)
        const int t0 = bid / nz;
        const int grp = t0 / (4 * npn);       // GROUP_M = 4
        m0 = (grp * 4 + (t0 % 4)) * 128;
        n0 = ((t0 / 4) % npn) * BN;
    } else {
        bz = blockIdx.z;
        m0 = blockIdx.y * 128;
        n0 = blockIdx.x * BN;
    }
    A += sA * bz;  B += sB * bz;  C += sC * bz;

    const int t = threadIdx.x;
    const int lane = t & 63;
    const int w = t >> 6;                    // wave id 0..3
    const int wm = (w >> 1) * 64;            // wave row offset
    const int wn = (w & 1) * (BN / 2);       // wave col offset

    f32x4 acc[4][NF] = {};

    const bf16* Ag = A + (long long)m0 * K;
    const bf16* Bg = B + (long long)n0 * K;
    // staging: idx = c*256+t -> row = idx>>3 ; SWIZZLED source col8 = (t&7)^(row&7)
    const int trow = t >> 3;
    const int tcol = (t & 7) ^ (trow & 7);
    char* AsB = (char*)As + (size_t)w * 1024;    // + c*4096 per call (wave-uniform)
    char* BsB = (char*)Bs + (size_t)w * 1024;

    for (int k0 = 0; k0 < K; k0 += 64) {
        __syncthreads();   // protect LDS while other waves still compute
        const bf16* a_src = Ag + (long long)trow * K + k0 + tcol * 8;
        const bf16* b_src = Bg + (long long)trow * K + k0 + tcol * 8;
#pragma unroll
        for (int c = 0; c < 4; ++c)
            async_cp16(a_src + (long long)(c * 32) * K, AsB + c * 4096);
#pragma unroll
        for (int c = 0; c < NF; ++c)
            async_cp16(b_src + (long long)(c * 32) * K, BsB + c * 4096);
        __syncthreads();   // vmcnt(0) drain before s_barrier

        const int rl = lane & 15;
        const int quad = lane >> 4;
        const int sw = rl & 7;
#pragma unroll
        for (int kk = 0; kk < 64; kk += 32) {
            const int c8 = (kk >> 3) + quad;          // logical col8
            const int ko = ((c8 ^ sw) << 3);          // physical element offset
            s16x8 af[4], bfr[NF];
#pragma unroll
            for (int i = 0; i < 4; ++i)
                af[i] = *(const s16x8*)(As + (wm + i * 16 + rl) * 64 + ko);
#pragma unroll
            for (int j = 0; j < NF; ++j)
                bfr[j] = *(const s16x8*)(Bs + (wn + j * 16 + rl) * 64 + ko);
#pragma unroll
            for (int i = 0; i < 4; ++i)
#pragma unroll
                for (int j = 0; j < NF; ++j)
                    acc[i][j] = __builtin_amdgcn_mfma_f32_16x16x32_bf16(
                        af[i], bfr[j], acc[i][j], 0, 0, 0);
        }
    }

    // epilogue: D row = (lane>>4)*4 + r, col = lane&15  (verified m89/m91)
    const int cl = lane & 15;
    const int rquad = (lane >> 4) << 2;
#pragma unroll
    for (int tn = 0; tn < NF; ++tn) {
        const int col = n0 + wn + tn * 16 + cl;
        if constexpr (EXP) {
            float csum = 0.f;
#pragma unroll
            for (int tm = 0; tm < 4; ++tm) {
#pragma unroll
                for (int r = 0; r < 4; ++r) {
                    const int row = m0 + wm + tm * 16 + rquad + r;
                    float v = __expf(acc[tm][tn][r] * scale);
                    csum += v;
                    storeC(C + (long long)row * N + col, v);
                }
            }
            csum += __shfl_xor(csum, 16);
            csum += __shfl_xor(csum, 32);
            if ((lane >> 4) == 0)
                atomicAdd(&colsum[(long long)bz * N + col], csum);
        } else {
            float bcol = 0.f;
            if constexpr (BIAS == 1) bcol = bias[col];
#pragma unroll
            for (int tm = 0; tm < 4; ++tm) {
#pragma unroll
                for (int r = 0; r < 4; ++r) {
                    const int row = m0 + wm + tm * 16 + rquad + r;
                    float v = acc[tm][tn][r] * scale;
                    if constexpr (BIAS == 1) v += bcol;
                    if constexpr (BIAS == 2) v += bias[row];
                    storeC(C + (long long)row * N + col, v);
                }
            }
        }
    }
}

// ---------------------------------------------------------------------------
extern "C" void kernel_launch(void* const* d_in, const int* in_sizes, int n_in,
                              void* d_out, int out_size, void* d_ws, size_t ws_size,
                              hipStream_t stream)
{
    constexpr int Bb = 8, NK = 2048, NQ = 2048, D = 256, H = 1024;
    const float scale = 0.03125f;   // 1/sqrt(1024)
    constexpr size_t E1  = (size_t)Bb * NK * H;   // 16,777,216 elems (33.55 MB bf16)
    constexpr size_t ES  = (size_t)NK * NQ;       // 4,194,304 elems per batch
    constexpr size_t EV  = (size_t)H * NK;        // 2,097,152 elems per batch
    constexpr size_t BIG = (size_t)Bb * NK * D;   // 4,194,304 elems
    constexpr size_t WSZ = (size_t)H * D;         // 262,144 elems
    constexpr size_t MISC = 4 * WSZ * 2 + 8 * NK * 4 + 256;  // weights + colsum

    const float* KEY   = (const float*)d_in[0];
    const float* VALUE = (const float*)d_in[1];
    const float* QUERY = (const float*)d_in[2];
    const float* Wk_w  = (const float*)d_in[3];
    const float* Wk_b  = (const float*)d_in[4];
    const float* Wq_w  = (const float*)d_in[5];
    const float* Wq_b  = (const float*)d_in[6];
    const float* Wv_w  = (const float*)d_in[7];
    const float* Wv_b  = (const float*)d_in[8];
    const float* lin_w = (const float*)d_in[9];
    const float* lin_b = (const float*)d_in[10];
    float* out = (float*)d_out;

    // group size: largest g whose workspace fits (deterministic across calls)
    auto need = [&](int g) -> size_t {
        return 3 * E1 * 2 + (g < 8 ? E1 * 2 : 0)
             + (size_t)g * ES * 2 + (size_t)g * EV * 2 + MISC;
    };
    const int g = (ws_size >= need(8)) ? 8 : (ws_size >= need(4)) ? 4 : 2;

    char* ws = (char*)d_ws;
    bf16* Kp   = (bf16*)ws;  ws += E1 * 2;
    bf16* Qp   = (bf16*)ws;  ws += E1 * 2;
    bf16* VpT  = (bf16*)ws;  ws += E1 * 2;                 // [b][h][i]
    bf16* ctx  = Kp;                                       // g==8: alias dead Kp
    if (g < 8) { ctx = (bf16*)ws; ws += E1 * 2; }
    bf16* Sg   = (bf16*)ws;  ws += (size_t)g * ES * 2;     // STexp[k,i], bf16
    bf16* VpS  = (bf16*)ws;  ws += (size_t)g * EV * 2;     // normalized V^T
    float* csm = (float*)ws; ws += (size_t)8 * NK * 4;     // column sums
    bf16* Wkb  = (bf16*)ws;  ws += WSZ * 2;
    bf16* Wqb  = (bf16*)ws;  ws += WSZ * 2;
    bf16* Wvb  = (bf16*)ws;  ws += WSZ * 2;
    bf16* linb = (bf16*)ws;  ws += WSZ * 2;
    // bf16 input copies overlay Sg(+VpS): fully consumed by GEMMs 1-3 before
    // Sg/VpS are first written (stream-ordered). Sg+VpS >= 25.2 MB for all g.
    bf16* KEYb = Sg;
    bf16* VALb = KEYb + BIG;
    bf16* QRYb = VALb + BIG;

    dim3 blk(256);

    // 0: convert f32 -> bf16 (KEY/VALUE/QUERY contiguous; 4 weights contiguous)
    {
        const int n4b = (int)(BIG / 4), n4w = (int)(WSZ / 4);
        cvt3_kernel<<<dim3(n4b / 256, 3), blk, 0, stream>>>(KEY, VALUE, QUERY, KEYb, n4b);
        cvt4_kernel<<<dim3(n4w / 256, 4), blk, 0, stream>>>(Wk_w, Wq_w, Wv_w, lin_w, Wkb, n4w);
    }

    // 1,2: projections K,Q  (M=16384, N=H, K=D) + col bias
    gemm_nt<bf16, 1, 128><<<dim3(H / 128, Bb * NK / 128, 1), blk, 0, stream>>>(
        KEYb, Wkb, Kp, Wk_b, nullptr, Bb * NK, H, D, 0, 0, 0, 1.0f, 1, 1);
    gemm_nt<bf16, 1, 128><<<dim3(H / 128, Bb * NQ / 128, 1), blk, 0, stream>>>(
        QRYb, Wqb, Qp, Wq_b, nullptr, Bb * NQ, H, D, 0, 0, 0, 1.0f, 1, 1);

    // 3: VpT[b,h,i] = Wv_w @ VALUE[b]^T + Wv_b(row)   (M=H, N=NK, K=D, z=batch)
    gemm_nt<bf16, 2, 128><<<dim3(NK / 128, H / 128, Bb), blk, 0, stream>>>(
        Wvb, VALb, VpT, Wv_b, nullptr, H, NK, D,
        0, (long long)NK * D, (long long)H * NK, 1.0f, 1, 1);

    // 4..6 per group of g batches
    for (int b0 = 0; b0 < Bb; b0 += g) {
        // 4a: zero column sums
        zero_kernel<<<dim3((g * NK / 4 + 255) / 256), blk, 0, stream>>>(csm, g * NK / 4);
        // 4b: STexp[k,i] = exp(scale * Qp[b] @ Kp[b]^T), colsum[i] += ...
        gemm_nt<bf16, 0, 128, 1, 1><<<dim3(g * (NQ / 128) * (NK / 128)), blk, 0, stream>>>(
            Qp + (size_t)b0 * NQ * H, Kp + (size_t)b0 * NK * H, Sg, nullptr, csm,
            NQ, NK, H,
            (long long)NQ * H, (long long)NK * H, (long long)NQ * NK, scale,
            g, NK / 128);
        // 5: VpS[h,i] = VpT[h,i] / colsum[i]
        scale_cols_kernel<<<dim3((int)(g * EV / 8 / 256)), blk, 0, stream>>>(
            VpT + (size_t)b0 * EV, csm, VpS, (int)EV, NK);
        // 6: ctx[k,h] = STexp @ VpS^T   (M=NQ, N=H, K=NK, swizzled, z=bid%g)
        gemm_nt<bf16, 0, 128, 1><<<dim3(g * (NQ / 128) * (H / 128)), blk, 0, stream>>>(
            Sg, VpS, ctx + (size_t)b0 * NQ * H, nullptr, nullptr,
            NQ, H, NK,
            (long long)NQ * NK, (long long)H * NK, (long long)NQ * H, 1.0f,
            g, H / 128);
    }

    // 7: out = ctx @ lin_w^T + lin_b   (M=16384, N=D, K=H) -> f32 d_out, BN=64
    gemm_nt<float, 1, 64><<<dim3(D / 64, Bb * NQ / 128, 1), blk, 0, stream>>>(
        ctx, linb, out, lin_b, nullptr, Bb * NQ, D, H, 0, 0, 0, 1.0f, 1, 1);
}